// Round 3
// baseline (560.418 us; speedup 1.0000x reference)
//
#include <hip/hip_runtime.h>
#include <hip/hip_fp16.h>

// VQC statevector simulator, register-resident, v3.
// One block = one batch sample. 512 threads x 32 complex amps/thread = 2^14.
// Layout L1: canonical i = o*512 + t  (bits 0-5 = lane, 6-8 = wave, 9-13 = reg o)
// Layout L0: canonical j = t*32 + o   (bits 0-4 = reg o, 5-10 = lane, 11-13 = wave)
// CNOT chain (c=i,t=i+1, i=0..12) == prefix-XOR permutation;
// inverse: src = (j ^ (j<<1)) & 0x3FFF. Layer 0's perm is fused into the
// encoding (permuted product state built directly in L0 registers).
// LDS holds fp16-packed state (64 KB) only during re-layout sweeps.
// launch_bounds(512,4): VGPR cap 128 (no spill), 2 blocks/CU (128 KB LDS).

constexpr int NQ  = 14;
constexpr int DIM = 1 << NQ;     // 16384
constexpr int NT  = 512;         // threads per block (8 waves)
constexpr int APT = DIM / NT;    // 32 amps per thread
constexpr int NL  = 4;

static __device__ __forceinline__ int swz(int idx) { return idx ^ ((idx >> 6) & 31); }

__global__ __launch_bounds__(NT, 4)
void vqc_kernel(const float* __restrict__ inputs,
                const float* __restrict__ weights,
                float* __restrict__ out)
{
    extern __shared__ __half2 lds[];   // DIM entries = 64 KB
    const int t    = threadIdx.x;
    const int b    = blockIdx.x;
    const int lane = t & 63;
    const int wv   = t >> 6;

    float ar[APT], ai[APT];

    // ---- Encoding fused with layer-0 CNOT perm: build P|psi_enc> directly in L0.
    // amp(j) = prod_q ry_q[src_q],  src = (j ^ (j<<1)) & 0x3FFF.
    {
        float cs[NQ], sn[NQ];
#pragma unroll
        for (int q = 0; q < NQ; ++q)
            __sincosf(0.5f * inputs[b * NQ + q], &sn[q], &cs[q]);

        const int jbase = t * APT;
        // src bits 6..13 are o-independent (o occupies j bits 0-4; src_k = j_k ^ j_{k-1})
        const int srchi = (jbase ^ (jbase << 1)) & (DIM - 1);
        float base = 1.0f;
#pragma unroll
        for (int q = 6; q < NQ; ++q)
            base *= ((srchi >> q) & 1) ? sn[q] : cs[q];
#pragma unroll
        for (int o = 0; o < APT; ++o) {
            int j   = jbase + o;
            int src = (j ^ (j << 1)) & (DIM - 1);
            float v = base;
#pragma unroll
            for (int q = 0; q < 6; ++q)
                v *= ((src >> q) & 1) ? sn[q] : cs[q];
            ar[o] = v;
            ai[o] = 0.0f;
        }
    }

    // ---- Variational layers. State enters each iteration in L0 (perm applied). ----
#pragma unroll 1
    for (int layer = 0; layer < NL; ++layer) {
        const float* wl = weights + layer * NQ;

        if (layer > 0) {
            // Sweep A: state (L1) -> LDS -> read with CNOT-chain perm into L0
            __syncthreads();
#pragma unroll
            for (int o = 0; o < APT; ++o)
                lds[swz(o * NT + t)] = __floats2half2_rn(ar[o], ai[o]);
            __syncthreads();
#pragma unroll
            for (int o = 0; o < APT; ++o) {
                int j   = t * APT + o;
                int src = (j ^ (j << 1)) & (DIM - 1);
                float2 f = __half22float2(lds[swz(src)]);
                ar[o] = f.x; ai[o] = f.y;
            }
        }

        // RX on qubits 0..4 (register-local bits of o in L0)
#pragma unroll
        for (int q = 0; q < 5; ++q) {
            float s, c;
            __sincosf(0.5f * wl[q], &s, &c);
#pragma unroll
            for (int o = 0; o < APT; ++o) {
                if (o & (1 << q)) continue;
                int o1 = o | (1 << q);
                float a0r = ar[o],  a0i = ai[o];
                float a1r = ar[o1], a1i = ai[o1];
                ar[o]  = c * a0r + s * a1i;
                ai[o]  = c * a0i - s * a1r;
                ar[o1] = c * a1r + s * a0i;
                ai[o1] = c * a1i - s * a0r;
            }
        }

        // RX on qubits 5..10 (lane bits 0..5 in L0) via shuffles.
        // RX is symmetric: mine' = c*mine - i*s*partner for both sides.
#pragma unroll
        for (int q = 5; q < 11; ++q) {
            float s, c;
            __sincosf(0.5f * wl[q], &s, &c);
            const int mask = 1 << (q - 5);
#pragma unroll
            for (int o = 0; o < APT; ++o) {
                float pr = __shfl_xor(ar[o], mask, 64);
                float pi = __shfl_xor(ai[o], mask, 64);
                ar[o] = c * ar[o] + s * pi;
                ai[o] = c * ai[o] - s * pr;
            }
        }

        // Sweep B: transpose L0 -> L1
        __syncthreads();
#pragma unroll
        for (int o = 0; o < APT; ++o)
            lds[swz(t * APT + o)] = __floats2half2_rn(ar[o], ai[o]);
        __syncthreads();
#pragma unroll
        for (int o = 0; o < APT; ++o) {
            float2 f = __half22float2(lds[swz(o * NT + t)]);
            ar[o] = f.x; ai[o] = f.y;
        }

        // RX on qubits 11..13 (reg bits 2..4 of o in L1; canonical bits 9-13 = o bits 0-4)
#pragma unroll
        for (int q = 11; q < NQ; ++q) {
            float s, c;
            __sincosf(0.5f * wl[q], &s, &c);
            const int bit = q - 9;
#pragma unroll
            for (int o = 0; o < APT; ++o) {
                if (o & (1 << bit)) continue;
                int o1 = o | (1 << bit);
                float a0r = ar[o],  a0i = ai[o];
                float a1r = ar[o1], a1i = ai[o1];
                ar[o]  = c * a0r + s * a1i;
                ai[o]  = c * a0i - s * a1r;
                ar[o1] = c * a1r + s * a0i;
                ai[o1] = c * a1i - s * a0r;
            }
        }
    }

    // ---- Z expectations. State in L1: canonical bits 0-5 = lane, 6-8 = wave,
    //      9-13 = o bits 0-4. ----
    float ptot = 0.0f, Sq[5] = {0, 0, 0, 0, 0};
#pragma unroll
    for (int o = 0; o < APT; ++o) {
        float p = ar[o] * ar[o] + ai[o] * ai[o];
        ptot += p;
#pragma unroll
        for (int m = 0; m < 5; ++m)
            Sq[m] += ((o >> m) & 1) ? -p : p;
    }

    // Wave-level butterfly: plain sums for ptot/Sq, signed (Walsh) for lane qubits 0..5.
    float accL[6];
#pragma unroll
    for (int k = 0; k < 6; ++k) accL[k] = ptot;
#pragma unroll
    for (int k = 0; k < 6; ++k) {
        const int m = 1 << k;
#pragma unroll
        for (int j = 0; j < 6; ++j) {
            float pr = __shfl_xor(accL[j], m, 64);
            if (j == k)
                accL[j] = ((lane >> k) & 1) ? (pr - accL[j]) : (accL[j] - pr);
            else
                accL[j] += pr;
        }
        ptot += __shfl_xor(ptot, m, 64);
#pragma unroll
        for (int j = 0; j < 5; ++j) Sq[j] += __shfl_xor(Sq[j], m, 64);
    }

    // Per-wave partials -> LDS, tiny cross-wave combine (8 waves x 12 floats).
    float* red = reinterpret_cast<float*>(lds);
    __syncthreads();                      // LDS no longer needed for state
    if (lane == 0) {
        red[wv * 12 + 0] = ptot;
#pragma unroll
        for (int k = 0; k < 6; ++k) red[wv * 12 + 1 + k] = accL[k];   // qubits 0..5
#pragma unroll
        for (int m = 0; m < 5; ++m) red[wv * 12 + 7 + m] = Sq[m];     // qubits 9..13
    }
    __syncthreads();

    if (t < NQ) {
        float acc = 0.0f;
        if (t < 6) {
            for (int w = 0; w < 8; ++w) acc += red[w * 12 + 1 + t];
        } else if (t < 9) {
            const int bit = t - 6;
            for (int w = 0; w < 8; ++w) {
                float v = red[w * 12];
                acc += ((w >> bit) & 1) ? -v : v;
            }
        } else {
            for (int w = 0; w < 8; ++w) acc += red[w * 12 + 7 + (t - 9)];
        }
        out[b * NQ + t] = acc;
    }
}

extern "C" void kernel_launch(void* const* d_in, const int* in_sizes, int n_in,
                              void* d_out, int out_size, void* d_ws, size_t ws_size,
                              hipStream_t stream)
{
    const float* inputs  = (const float*)d_in[0];
    const float* weights = (const float*)d_in[1];
    float* out = (float*)d_out;

    const int Bn = in_sizes[0] / NQ;   // 1024
    vqc_kernel<<<dim3(Bn), dim3(NT), DIM * sizeof(__half2), stream>>>(inputs, weights, out);
}

// Round 4
// 248.974 us; speedup vs baseline: 2.2509x; 2.2509x over previous
//
#include <hip/hip_runtime.h>
#include <hip/hip_fp16.h>

// VQC statevector simulator, register-resident, v4.
// v3 -> v4: ONLY change is __launch_bounds__(512, 2). Empirical law from
// R1-R3 counters: hipcc VGPR cap = 256 / waves_per_eu_arg. arg=4 capped us
// at 64 VGPRs (< 64 regs of state alone -> total spill, 2.2 GB HBM traffic).
// arg=2 -> cap 128: 64 state + ~40 temps fits, zero spill, and still meets
// the LDS-bound occupancy (2 blocks/CU = 4 waves/SIMD needs exactly 128).
//
// One block = one batch sample. 512 threads x 32 complex amps/thread = 2^14.
// Layout L1: canonical i = o*512 + t  (bits 0-5 = lane, 6-8 = wave, 9-13 = reg o)
// Layout L0: canonical j = t*32 + o   (bits 0-4 = reg o, 5-10 = lane, 11-13 = wave)
// CNOT chain (c=i,t=i+1, i=0..12) == prefix-XOR permutation;
// inverse: src = (j ^ (j<<1)) & 0x3FFF. Layer 0's perm is fused into the
// encoding (permuted product state built directly in L0 registers).
// LDS holds fp16-packed state (64 KB) only during re-layout sweeps; all four
// sweep patterns are <=2-way bank aliasing under swz() (GF(2) rank-checked).

constexpr int NQ  = 14;
constexpr int DIM = 1 << NQ;     // 16384
constexpr int NT  = 512;         // threads per block (8 waves)
constexpr int APT = DIM / NT;    // 32 amps per thread
constexpr int NL  = 4;

static __device__ __forceinline__ int swz(int idx) { return idx ^ ((idx >> 6) & 31); }

__global__ __launch_bounds__(NT, 2)
void vqc_kernel(const float* __restrict__ inputs,
                const float* __restrict__ weights,
                float* __restrict__ out)
{
    extern __shared__ __half2 lds[];   // DIM entries = 64 KB
    const int t    = threadIdx.x;
    const int b    = blockIdx.x;
    const int lane = t & 63;
    const int wv   = t >> 6;

    float ar[APT], ai[APT];

    // ---- Encoding fused with layer-0 CNOT perm: build P|psi_enc> directly in L0.
    // amp(j) = prod_q ry_q[src_q],  src = (j ^ (j<<1)) & 0x3FFF.
    {
        float cs[NQ], sn[NQ];
#pragma unroll
        for (int q = 0; q < NQ; ++q)
            __sincosf(0.5f * inputs[b * NQ + q], &sn[q], &cs[q]);

        const int jbase = t * APT;
        // src bits 6..13 are o-independent (o occupies j bits 0-4; src_k = j_k ^ j_{k-1})
        const int srchi = (jbase ^ (jbase << 1)) & (DIM - 1);
        float base = 1.0f;
#pragma unroll
        for (int q = 6; q < NQ; ++q)
            base *= ((srchi >> q) & 1) ? sn[q] : cs[q];
#pragma unroll
        for (int o = 0; o < APT; ++o) {
            int j   = jbase + o;
            int src = (j ^ (j << 1)) & (DIM - 1);
            float v = base;
#pragma unroll
            for (int q = 0; q < 6; ++q)
                v *= ((src >> q) & 1) ? sn[q] : cs[q];
            ar[o] = v;
            ai[o] = 0.0f;
        }
    }

    // ---- Variational layers. State enters each iteration in L0 (perm applied). ----
#pragma unroll 1
    for (int layer = 0; layer < NL; ++layer) {
        const float* wl = weights + layer * NQ;

        if (layer > 0) {
            // Sweep A: state (L1) -> LDS -> read with CNOT-chain perm into L0
            __syncthreads();
#pragma unroll
            for (int o = 0; o < APT; ++o)
                lds[swz(o * NT + t)] = __floats2half2_rn(ar[o], ai[o]);
            __syncthreads();
#pragma unroll
            for (int o = 0; o < APT; ++o) {
                int j   = t * APT + o;
                int src = (j ^ (j << 1)) & (DIM - 1);
                float2 f = __half22float2(lds[swz(src)]);
                ar[o] = f.x; ai[o] = f.y;
            }
        }

        // RX on qubits 0..4 (register-local bits of o in L0)
#pragma unroll
        for (int q = 0; q < 5; ++q) {
            float s, c;
            __sincosf(0.5f * wl[q], &s, &c);
#pragma unroll
            for (int o = 0; o < APT; ++o) {
                if (o & (1 << q)) continue;
                int o1 = o | (1 << q);
                float a0r = ar[o],  a0i = ai[o];
                float a1r = ar[o1], a1i = ai[o1];
                ar[o]  = c * a0r + s * a1i;
                ai[o]  = c * a0i - s * a1r;
                ar[o1] = c * a1r + s * a0i;
                ai[o1] = c * a1i - s * a0r;
            }
        }

        // RX on qubits 5..10 (lane bits 0..5 in L0) via shuffles.
        // RX is symmetric: mine' = c*mine - i*s*partner for both sides.
#pragma unroll
        for (int q = 5; q < 11; ++q) {
            float s, c;
            __sincosf(0.5f * wl[q], &s, &c);
            const int mask = 1 << (q - 5);
#pragma unroll
            for (int o = 0; o < APT; ++o) {
                float pr = __shfl_xor(ar[o], mask, 64);
                float pi = __shfl_xor(ai[o], mask, 64);
                ar[o] = c * ar[o] + s * pi;
                ai[o] = c * ai[o] - s * pr;
            }
        }

        // Sweep B: transpose L0 -> L1
        __syncthreads();
#pragma unroll
        for (int o = 0; o < APT; ++o)
            lds[swz(t * APT + o)] = __floats2half2_rn(ar[o], ai[o]);
        __syncthreads();
#pragma unroll
        for (int o = 0; o < APT; ++o) {
            float2 f = __half22float2(lds[swz(o * NT + t)]);
            ar[o] = f.x; ai[o] = f.y;
        }

        // RX on qubits 11..13 (reg bits 2..4 of o in L1; canonical bits 9-13 = o bits 0-4)
#pragma unroll
        for (int q = 11; q < NQ; ++q) {
            float s, c;
            __sincosf(0.5f * wl[q], &s, &c);
            const int bit = q - 9;
#pragma unroll
            for (int o = 0; o < APT; ++o) {
                if (o & (1 << bit)) continue;
                int o1 = o | (1 << bit);
                float a0r = ar[o],  a0i = ai[o];
                float a1r = ar[o1], a1i = ai[o1];
                ar[o]  = c * a0r + s * a1i;
                ai[o]  = c * a0i - s * a1r;
                ar[o1] = c * a1r + s * a0i;
                ai[o1] = c * a1i - s * a0r;
            }
        }
    }

    // ---- Z expectations. State in L1: canonical bits 0-5 = lane, 6-8 = wave,
    //      9-13 = o bits 0-4. ----
    float ptot = 0.0f, Sq[5] = {0, 0, 0, 0, 0};
#pragma unroll
    for (int o = 0; o < APT; ++o) {
        float p = ar[o] * ar[o] + ai[o] * ai[o];
        ptot += p;
#pragma unroll
        for (int m = 0; m < 5; ++m)
            Sq[m] += ((o >> m) & 1) ? -p : p;
    }

    // Wave-level butterfly: plain sums for ptot/Sq, signed (Walsh) for lane qubits 0..5.
    float accL[6];
#pragma unroll
    for (int k = 0; k < 6; ++k) accL[k] = ptot;
#pragma unroll
    for (int k = 0; k < 6; ++k) {
        const int m = 1 << k;
#pragma unroll
        for (int j = 0; j < 6; ++j) {
            float pr = __shfl_xor(accL[j], m, 64);
            if (j == k)
                accL[j] = ((lane >> k) & 1) ? (pr - accL[j]) : (accL[j] - pr);
            else
                accL[j] += pr;
        }
        ptot += __shfl_xor(ptot, m, 64);
#pragma unroll
        for (int j = 0; j < 5; ++j) Sq[j] += __shfl_xor(Sq[j], m, 64);
    }

    // Per-wave partials -> LDS, tiny cross-wave combine (8 waves x 12 floats).
    float* red = reinterpret_cast<float*>(lds);
    __syncthreads();                      // LDS no longer needed for state
    if (lane == 0) {
        red[wv * 12 + 0] = ptot;
#pragma unroll
        for (int k = 0; k < 6; ++k) red[wv * 12 + 1 + k] = accL[k];   // qubits 0..5
#pragma unroll
        for (int m = 0; m < 5; ++m) red[wv * 12 + 7 + m] = Sq[m];     // qubits 9..13
    }
    __syncthreads();

    if (t < NQ) {
        float acc = 0.0f;
        if (t < 6) {
            for (int w = 0; w < 8; ++w) acc += red[w * 12 + 1 + t];
        } else if (t < 9) {
            const int bit = t - 6;
            for (int w = 0; w < 8; ++w) {
                float v = red[w * 12];
                acc += ((w >> bit) & 1) ? -v : v;
            }
        } else {
            for (int w = 0; w < 8; ++w) acc += red[w * 12 + 7 + (t - 9)];
        }
        out[b * NQ + t] = acc;
    }
}

extern "C" void kernel_launch(void* const* d_in, const int* in_sizes, int n_in,
                              void* d_out, int out_size, void* d_ws, size_t ws_size,
                              hipStream_t stream)
{
    const float* inputs  = (const float*)d_in[0];
    const float* weights = (const float*)d_in[1];
    float* out = (float*)d_out;

    const int Bn = in_sizes[0] / NQ;   // 1024
    vqc_kernel<<<dim3(Bn), dim3(NT), DIM * sizeof(__half2), stream>>>(inputs, weights, out);
}

// Round 5
// 151.711 us; speedup vs baseline: 3.6940x; 1.6411x over previous
//
#include <hip/hip_runtime.h>
#include <hip/hip_fp16.h>

// VQC statevector simulator, v5: shuffle-free 3-layout scheme.
// v4 counters showed residual spill (87 MB scratch writes) from shuffle-temp
// live ranges, and a DS-pipe load of ~2000 ops/thread (1536 ds_bpermute).
// v5 retires all 14 RX qubits via register-local butterflies across three
// layouts, connected by LDS sweeps (704 DS ops/thread, 2.8x fewer):
//   L0: canonical n = (t<<5)|o          (o bits = qubits 0-4)
//   L2: n = ((t>>5)<<10)|(o<<5)|(t&31)  (o bits = qubits 5-9)
//   L1: n = (o<<9)|t                    (o bits = qubits 9-13)
// Per layer: [perm sweep L1->L0] RX0-4, [S1 L0->L2] RX5-9, [S2 L2->L1] RX10-13.
// CNOT chain == prefix-XOR perm, src = (j ^ (j<<1)) & 0x3FFF (validated R1-R4);
// layer 0's perm is fused into the product-state encoding.
// LDS: fp16-packed state, 64 KB. Swizzle swz(n) = n ^ ((n>>6)&31) folded into
// per-thread constants: every DS address is C_thread ^ K(o) with K(o) a
// compile-time literal (1 VALU per access). All patterns <=2-way bank aliasing.

constexpr int NQ  = 14;
constexpr int DIM = 1 << NQ;     // 16384
constexpr int NT  = 512;         // 8 waves
constexpr int APT = DIM / NT;    // 32
constexpr int NL  = 4;

__global__ __launch_bounds__(NT, 2)
void vqc_kernel(const float* __restrict__ inputs,
                const float* __restrict__ weights,
                float* __restrict__ out)
{
    extern __shared__ __half2 lds[];   // DIM half2 = 64 KB
    const int t    = threadIdx.x;
    const int b    = blockIdx.x;
    const int lane = t & 63;
    const int wv   = t >> 6;

    // Thread constants with swizzle pre-folded (half2-index space).
    const int C_L0 = (t << 5) | ((t >> 1) & 31);                       // S1 write:  addr = C_L0 ^ o
    const int Tp   = ((t << 5) ^ (t << 6)) & (DIM - 1);
    const int C_PR = Tp ^ ((Tp >> 6) & 31);                            // perm read: addr = C_PR ^ (o ^ (o<<1))
    const int C_L2 = (((t >> 5) << 10) | (t & 31)) ^ (((t >> 5) & 1) << 4); // L2: addr = C_L2 ^ ((o<<5)|(o>>1))
    const int C_L1 = t ^ ((t >> 6) & 7);                               // L1: addr = C_L1 ^ ((o<<9)|((o&3)<<3))

    float ar[APT], ai[APT];

    // ---- Encoding fused with layer-0 CNOT perm: product state built in L0 ----
    {
        float cs[NQ], sn[NQ];
#pragma unroll
        for (int q = 0; q < NQ; ++q)
            __sincosf(0.5f * inputs[b * NQ + q], &sn[q], &cs[q]);

        const int jbase = t << 5;
        const int srchi = (jbase ^ (jbase << 1)) & (DIM - 1);
        float base = 1.0f;
#pragma unroll
        for (int q = 6; q < NQ; ++q)
            base *= ((srchi >> q) & 1) ? sn[q] : cs[q];
#pragma unroll
        for (int o = 0; o < APT; ++o) {
            int j   = jbase | o;
            int src = (j ^ (j << 1)) & (DIM - 1);
            float v = base;
#pragma unroll
            for (int q = 0; q < 6; ++q)
                v *= ((src >> q) & 1) ? sn[q] : cs[q];
            ar[o] = v;
            ai[o] = 0.0f;
        }
    }

    // ---- Variational layers ----
#pragma unroll 1
    for (int layer = 0; layer < NL; ++layer) {
        const float* wl = weights + layer * NQ;

        if (layer > 0) {
            // Perm sweep: L1 -> LDS -> L0 with CNOT-chain permutation
            __syncthreads();
#pragma unroll
            for (int o = 0; o < APT; ++o)
                lds[C_L1 ^ ((o << 9) | ((o & 3) << 3))] = __floats2half2_rn(ar[o], ai[o]);
            __syncthreads();
#pragma unroll
            for (int o = 0; o < APT; ++o) {
                float2 f = __half22float2(lds[C_PR ^ (o ^ (o << 1))]);
                ar[o] = f.x; ai[o] = f.y;
            }
        }

        // RX on qubits 0..4 (o bits, layout L0)
#pragma unroll
        for (int q = 0; q < 5; ++q) {
            float s, c;
            __sincosf(0.5f * wl[q], &s, &c);
#pragma unroll
            for (int o = 0; o < APT; ++o) {
                if (o & (1 << q)) continue;
                int o1 = o | (1 << q);
                float a0r = ar[o],  a0i = ai[o];
                float a1r = ar[o1], a1i = ai[o1];
                ar[o]  = c * a0r + s * a1i;
                ai[o]  = c * a0i - s * a1r;
                ar[o1] = c * a1r + s * a0i;
                ai[o1] = c * a1i - s * a0r;
            }
        }

        // Sweep S1: L0 -> LDS -> L2
        __syncthreads();
#pragma unroll
        for (int o = 0; o < APT; ++o)
            lds[C_L0 ^ o] = __floats2half2_rn(ar[o], ai[o]);
        __syncthreads();
#pragma unroll
        for (int o = 0; o < APT; ++o) {
            float2 f = __half22float2(lds[C_L2 ^ ((o << 5) | (o >> 1))]);
            ar[o] = f.x; ai[o] = f.y;
        }

        // RX on qubits 5..9 (o bits, layout L2)
#pragma unroll
        for (int q = 0; q < 5; ++q) {
            float s, c;
            __sincosf(0.5f * wl[5 + q], &s, &c);
#pragma unroll
            for (int o = 0; o < APT; ++o) {
                if (o & (1 << q)) continue;
                int o1 = o | (1 << q);
                float a0r = ar[o],  a0i = ai[o];
                float a1r = ar[o1], a1i = ai[o1];
                ar[o]  = c * a0r + s * a1i;
                ai[o]  = c * a0i - s * a1r;
                ar[o1] = c * a1r + s * a0i;
                ai[o1] = c * a1i - s * a0r;
            }
        }

        // Sweep S2: L2 -> LDS -> L1
        __syncthreads();
#pragma unroll
        for (int o = 0; o < APT; ++o)
            lds[C_L2 ^ ((o << 5) | (o >> 1))] = __floats2half2_rn(ar[o], ai[o]);
        __syncthreads();
#pragma unroll
        for (int o = 0; o < APT; ++o) {
            float2 f = __half22float2(lds[C_L1 ^ ((o << 9) | ((o & 3) << 3))]);
            ar[o] = f.x; ai[o] = f.y;
        }

        // RX on qubits 10..13 (o bits 1..4, layout L1; o bit 0 = qubit 9 done in L2)
#pragma unroll
        for (int q = 10; q < NQ; ++q) {
            float s, c;
            __sincosf(0.5f * wl[q], &s, &c);
            const int bit = q - 9;
#pragma unroll
            for (int o = 0; o < APT; ++o) {
                if (o & (1 << bit)) continue;
                int o1 = o | (1 << bit);
                float a0r = ar[o],  a0i = ai[o];
                float a1r = ar[o1], a1i = ai[o1];
                ar[o]  = c * a0r + s * a1i;
                ai[o]  = c * a0i - s * a1r;
                ar[o1] = c * a1r + s * a0i;
                ai[o1] = c * a1i - s * a0r;
            }
        }
    }

    // ---- Z expectations. State in L1: canonical bits 0-5 = lane, 6-8 = wave,
    //      9-13 = o bits 0-4. ----
    float ptot = 0.0f, Sq[5] = {0, 0, 0, 0, 0};
#pragma unroll
    for (int o = 0; o < APT; ++o) {
        float p = ar[o] * ar[o] + ai[o] * ai[o];
        ptot += p;
#pragma unroll
        for (int m = 0; m < 5; ++m)
            Sq[m] += ((o >> m) & 1) ? -p : p;
    }

    // Wave-level butterfly: plain sums for ptot/Sq, signed (Walsh) for lane qubits 0..5.
    float accL[6];
#pragma unroll
    for (int k = 0; k < 6; ++k) accL[k] = ptot;
#pragma unroll
    for (int k = 0; k < 6; ++k) {
        const int m = 1 << k;
#pragma unroll
        for (int j = 0; j < 6; ++j) {
            float pr = __shfl_xor(accL[j], m, 64);
            if (j == k)
                accL[j] = ((lane >> k) & 1) ? (pr - accL[j]) : (accL[j] - pr);
            else
                accL[j] += pr;
        }
        ptot += __shfl_xor(ptot, m, 64);
#pragma unroll
        for (int j = 0; j < 5; ++j) Sq[j] += __shfl_xor(Sq[j], m, 64);
    }

    // Per-wave partials -> LDS, tiny cross-wave combine (8 waves x 12 floats).
    float* red = reinterpret_cast<float*>(lds);
    __syncthreads();                      // LDS no longer needed for state
    if (lane == 0) {
        red[wv * 12 + 0] = ptot;
#pragma unroll
        for (int k = 0; k < 6; ++k) red[wv * 12 + 1 + k] = accL[k];   // qubits 0..5
#pragma unroll
        for (int m = 0; m < 5; ++m) red[wv * 12 + 7 + m] = Sq[m];     // qubits 9..13
    }
    __syncthreads();

    if (t < NQ) {
        float acc = 0.0f;
        if (t < 6) {
            for (int w = 0; w < 8; ++w) acc += red[w * 12 + 1 + t];
        } else if (t < 9) {
            const int bit = t - 6;
            for (int w = 0; w < 8; ++w) {
                float v = red[w * 12];
                acc += ((w >> bit) & 1) ? -v : v;
            }
        } else {
            for (int w = 0; w < 8; ++w) acc += red[w * 12 + 7 + (t - 9)];
        }
        out[b * NQ + t] = acc;
    }
}

extern "C" void kernel_launch(void* const* d_in, const int* in_sizes, int n_in,
                              void* d_out, int out_size, void* d_ws, size_t ws_size,
                              hipStream_t stream)
{
    const float* inputs  = (const float*)d_in[0];
    const float* weights = (const float*)d_in[1];
    float* out = (float*)d_out;

    const int Bn = in_sizes[0] / NQ;   // 1024
    vqc_kernel<<<dim3(Bn), dim3(NT), DIM * sizeof(__half2), stream>>>(inputs, weights, out);
}

// Round 6
// 114.051 us; speedup vs baseline: 4.9137x; 1.3302x over previous
//
#include <hip/hip_runtime.h>
#include <hip/hip_fp16.h>

// VQC statevector simulator, v6: double-buffered LDS (1 barrier/sweep, wave
// drift overlaps DS with VALU) + packed-fp32 butterflies (v_pk_fma_f32).
// v5 counters: zero spill, VALUBusy 70%, occupancy 22% (1 block/CU) ->
// phase-serialization of DS sweeps vs VALU butterflies was the bottleneck.
//
// One block = one sample. 512 threads x 32 amps (float2) = 2^14 state.
// Layouts (canonical index n, qubit q = bit q):
//   L0: n = (t<<5)|o          (o bits = qubits 0-4)
//   L2: n = ((t>>5)<<10)|(o<<5)|(t&31)  (o bits = qubits 5-9)
//   L1: n = (o<<9)|t          (o bits 1-4 = qubits 10-13)
// Per layer: [perm sweep L1->L0] RX0-4, [S1 L0->L2] RX5-9, [S2 L2->L1] RX10-13.
// CNOT chain == prefix-XOR perm, src = (j ^ (j<<1)) & 0x3FFF; layer-0 perm is
// fused into the product-state encoding. Swizzle swz(n)=n^((n>>6)&31) folded
// into per-thread constants (validated v5, absmax 3.9e-3). LDS = 2 x 64 KB
// double buffer: sweep = {write buf[p]; ONE barrier; read buf[p]; p^=1}.
// Safety: a wave writes buffer P for sweep s only after bar(s-1), which all
// waves reach only after their reads of sweep s-2 (same buffer P). 12
// barriers total vs 22 in v5; waves drift -> DS/VALU overlap across waves.

typedef float v2f __attribute__((ext_vector_type(2)));

constexpr int NQ  = 14;
constexpr int DIM = 1 << NQ;     // 16384
constexpr int NT  = 512;         // 8 waves
constexpr int APT = DIM / NT;    // 32
constexpr int NL  = 4;

// Packed butterfly: a0' = c*a0 + s*J(a1), a1' = c*a1 + s*J(a0),
// J(r,i) = (i,-r). Packed: fma((s,-s), a.yx, c*a) -> v_pk_mul + v_pk_fma.
#define RXREG(QBIT, ANGLE)                                              \
    {                                                                   \
        float s_, c_;                                                   \
        __sincosf(0.5f * (ANGLE), &s_, &c_);                            \
        v2f sp; sp.x = s_; sp.y = -s_;                                  \
        _Pragma("unroll")                                               \
        for (int o = 0; o < APT; ++o) {                                 \
            if (o & (1 << (QBIT))) continue;                            \
            const int o1 = o | (1 << (QBIT));                           \
            v2f w0 = a[o1].yx, w1 = a[o].yx;                            \
            a[o]  = __builtin_elementwise_fma(sp, w0, c_ * a[o]);       \
            a[o1] = __builtin_elementwise_fma(sp, w1, c_ * a[o1]);      \
        }                                                               \
    }

// One LDS round-trip re-layout: write buf[pb], one barrier, read buf[pb].
#define SWEEP(WADDR, RADDR)                                             \
    {                                                                   \
        __half2* buf = lds + pb * DIM;                                  \
        _Pragma("unroll")                                               \
        for (int o = 0; o < APT; ++o)                                   \
            buf[WADDR] = __floats2half2_rn(a[o].x, a[o].y);             \
        __syncthreads();                                                \
        _Pragma("unroll")                                               \
        for (int o = 0; o < APT; ++o) {                                 \
            float2 f_ = __half22float2(buf[RADDR]);                     \
            a[o].x = f_.x; a[o].y = f_.y;                               \
        }                                                               \
        pb ^= 1;                                                        \
    }

__global__ __launch_bounds__(NT, 1)
void vqc_kernel(const float* __restrict__ inputs,
                const float* __restrict__ weights,
                float* __restrict__ out)
{
    extern __shared__ __half2 lds[];   // 2*DIM half2 = 128 KB
    const int t    = threadIdx.x;
    const int b    = blockIdx.x;
    const int lane = t & 63;
    const int wv   = t >> 6;

    // Thread constants with swizzle pre-folded (half2-index space), from v5.
    const int C_L0 = (t << 5) | ((t >> 1) & 31);                       // S1 write:  C_L0 ^ o
    const int Tp   = ((t << 5) ^ (t << 6)) & (DIM - 1);
    const int C_PR = Tp ^ ((Tp >> 6) & 31);                            // perm read: C_PR ^ (o ^ (o<<1))
    const int C_L2 = (((t >> 5) << 10) | (t & 31)) ^ (((t >> 5) & 1) << 4); // C_L2 ^ ((o<<5)|(o>>1))
    const int C_L1 = t ^ ((t >> 6) & 7);                               // C_L1 ^ ((o<<9)|((o&3)<<3))

    v2f a[APT];

    // ---- Encoding fused with layer-0 CNOT perm: product state built in L0 ----
    {
        float cs[NQ], sn[NQ];
#pragma unroll
        for (int q = 0; q < NQ; ++q)
            __sincosf(0.5f * inputs[b * NQ + q], &sn[q], &cs[q]);

        const int jbase = t << 5;
        const int srchi = (jbase ^ (jbase << 1)) & (DIM - 1);
        float base = 1.0f;
#pragma unroll
        for (int q = 6; q < NQ; ++q)
            base *= ((srchi >> q) & 1) ? sn[q] : cs[q];
#pragma unroll
        for (int o = 0; o < APT; ++o) {
            int j   = jbase | o;
            int src = (j ^ (j << 1)) & (DIM - 1);
            float v = base;
#pragma unroll
            for (int q = 0; q < 6; ++q)
                v *= ((src >> q) & 1) ? sn[q] : cs[q];
            a[o].x = v;
            a[o].y = 0.0f;
        }
    }

    int pb = 0;   // LDS buffer parity; 11 sweeps total, last uses buf0.

    // ---- Variational layers ----
#pragma unroll 1
    for (int layer = 0; layer < NL; ++layer) {
        const float* wl = weights + layer * NQ;

        if (layer > 0) {
            // Perm sweep: L1 -> L0 with CNOT-chain permutation
            SWEEP(C_L1 ^ ((o << 9) | ((o & 3) << 3)), C_PR ^ (o ^ (o << 1)));
        }

        // RX qubits 0..4 (o bits, layout L0)
#pragma unroll
        for (int q = 0; q < 5; ++q) RXREG(q, wl[q]);

        // S1: L0 -> L2
        SWEEP(C_L0 ^ o, C_L2 ^ ((o << 5) | (o >> 1)));

        // RX qubits 5..9 (o bits, layout L2)
#pragma unroll
        for (int q = 0; q < 5; ++q) RXREG(q, wl[5 + q]);

        // S2: L2 -> L1
        SWEEP(C_L2 ^ ((o << 5) | (o >> 1)), C_L1 ^ ((o << 9) | ((o & 3) << 3)));

        // RX qubits 10..13 (o bits 1..4, layout L1)
#pragma unroll
        for (int q = 10; q < NQ; ++q) RXREG(q - 9, wl[q]);
    }

    // ---- Z expectations. State in L1: canonical bits 0-5 = lane, 6-8 = wave,
    //      9-13 = o bits 0-4. ----
    float ptot = 0.0f, Sq[5] = {0, 0, 0, 0, 0};
#pragma unroll
    for (int o = 0; o < APT; ++o) {
        float p = a[o].x * a[o].x + a[o].y * a[o].y;
        ptot += p;
#pragma unroll
        for (int m = 0; m < 5; ++m)
            Sq[m] += ((o >> m) & 1) ? -p : p;
    }

    // Wave-level butterfly: plain sums for ptot/Sq, signed (Walsh) for lane qubits 0..5.
    float accL[6];
#pragma unroll
    for (int k = 0; k < 6; ++k) accL[k] = ptot;
#pragma unroll
    for (int k = 0; k < 6; ++k) {
        const int m = 1 << k;
#pragma unroll
        for (int j = 0; j < 6; ++j) {
            float pr = __shfl_xor(accL[j], m, 64);
            if (j == k)
                accL[j] = ((lane >> k) & 1) ? (pr - accL[j]) : (accL[j] - pr);
            else
                accL[j] += pr;
        }
        ptot += __shfl_xor(ptot, m, 64);
#pragma unroll
        for (int j = 0; j < 5; ++j) Sq[j] += __shfl_xor(Sq[j], m, 64);
    }

    // Per-wave partials into buffer 1 (final sweep used buffer 0 -> no race).
    float* red = reinterpret_cast<float*>(lds + DIM);
    if (lane == 0) {
        red[wv * 12 + 0] = ptot;
#pragma unroll
        for (int k = 0; k < 6; ++k) red[wv * 12 + 1 + k] = accL[k];   // qubits 0..5
#pragma unroll
        for (int m = 0; m < 5; ++m) red[wv * 12 + 7 + m] = Sq[m];     // qubits 9..13
    }
    __syncthreads();

    if (t < NQ) {
        float acc = 0.0f;
        if (t < 6) {
            for (int w = 0; w < 8; ++w) acc += red[w * 12 + 1 + t];
        } else if (t < 9) {
            const int bit = t - 6;
            for (int w = 0; w < 8; ++w) {
                float v = red[w * 12];
                acc += ((w >> bit) & 1) ? -v : v;
            }
        } else {
            for (int w = 0; w < 8; ++w) acc += red[w * 12 + 7 + (t - 9)];
        }
        out[b * NQ + t] = acc;
    }
}

extern "C" void kernel_launch(void* const* d_in, const int* in_sizes, int n_in,
                              void* d_out, int out_size, void* d_ws, size_t ws_size,
                              hipStream_t stream)
{
    const float* inputs  = (const float*)d_in[0];
    const float* weights = (const float*)d_in[1];
    float* out = (float*)d_out;

    const int Bn = in_sizes[0] / NQ;   // 1024
    vqc_kernel<<<dim3(Bn), dim3(NT), 2 * DIM * sizeof(__half2), stream>>>(inputs, weights, out);
}